// Round 8
// baseline (397.443 us; speedup 1.0000x reference)
//
#include <hip/hip_runtime.h>
#include <hip/hip_bf16.h>
#include <cstdint>

constexpr int B_    = 4;
constexpr int NIN_  = 50000;
constexpr int NOUT_ = 50000;
constexpr int E_    = 819200;
constexpr int CI    = 16;
constexpr int CO    = 16;
constexpr int Hh    = 100;

constexpr int NBLK   = 256;           // persistent blocks (1 per CU)
constexpr int BITER  = E_ / 512;      // 1600 block-iterations (8 waves x 64 edges)
constexpr size_t LDS_BYTES = 163840;  // 128 KB weights + 8 waves x 4 KB xs

typedef __attribute__((ext_vector_type(8))) short bf16x8;
typedef __attribute__((ext_vector_type(4))) float f32x4;

union frag { bf16x8 v; unsigned u[4]; };

__device__ inline unsigned pk2(float a, float b) {
    unsigned r;
    asm("v_cvt_pk_bf16_f32 %0, %1, %2" : "=v"(r) : "v"(a), "v"(b));
    return r;
}

// 16B-chunk XOR bank swizzle within a 128-bf16 row (verified rounds 2-7)
__device__ inline int chunkXor(int r) { return ((r & 7) << 3) ^ ((r & 8) << 1); }
__device__ inline int swz(int r, int k) { return r * 128 + (k ^ chunkXor(r)); }

// sigma-wiring: out-wire at D(nt,kg,q) is consumed at k_eff = sigma(m) =
// (nt&3)*32 + kg*8 + (nt>>2)*4 + q ; prep bakes sigma^-1 into the weight image.

// ---------------- prep: swizzled+sigma'd bf16 weight image ------------------
__global__ __launch_bounds__(256)
void prep_kernel(const float* __restrict__ w1, const float* __restrict__ w2,
                 const float* __restrict__ w3, const float* __restrict__ w4,
                 const float* __restrict__ b1, const float* __restrict__ b2,
                 const float* __restrict__ b3, const float* __restrict__ b4,
                 unsigned short* __restrict__ wcat, unsigned short* __restrict__ W1T,
                 float* __restrict__ b1p, float* __restrict__ b2p,
                 float* __restrict__ b3p, float* __restrict__ b4p)
{
    const int i = blockIdx.x * 256 + threadIdx.x;
    auto bf = [](float f) {
        __hip_bfloat16 h = __float2bfloat16(f);
        return *reinterpret_cast<unsigned short*>(&h);
    };
    auto inv = [](int kpos) {   // sigma^-1
        return ((kpos >> 2) & 1) * 64 + ((kpos >> 5) & 3) * 16 +
               ((kpos >> 3) & 3) * 4 + (kpos & 3);
    };
    if (i < 32768) {                     // W2 [0,16384), W3 [16384,32768)
        int j = i & 16383; int r = j >> 7, kz = j & 127;
        int kpos = kz ^ chunkXor(r);
        int u = inv(kpos);
        const float* w = (i < 16384) ? w2 : w3;
        wcat[i] = (r < Hh && u < Hh) ? bf(w[u * Hh + r]) : (unsigned short)0;
    } else if (i < 65536) {              // W4: rows 256 x k 128
        int j = i - 32768; int r = j >> 7, kz = j & 127;
        int kpos = kz ^ chunkXor(r);
        int u = inv(kpos);
        wcat[i] = (u < Hh) ? bf(w4[u * 256 + r]) : (unsigned short)0;
    } else if (i < 69632) {              // W1T [wire:128][k:32]
        int j = i - 65536; int wi = j >> 5, k = j & 31;
        W1T[j] = (k < 6 && wi < Hh) ? bf(w1[k * Hh + wi]) : (unsigned short)0;
    } else if (i < 69760) { int j = i - 69632; b1p[j] = (j < Hh) ? b1[j] : 0.f; }
    else if (i < 69888) { int j = i - 69760; b2p[j] = (j < Hh) ? b2[j] : 0.f; }
    else if (i < 70016) { int j = i - 69888; b3p[j] = (j < Hh) ? b3[j] : 0.f; }
    else if (i < 70272) { int j = i - 70016; b4p[j] = b4[j]; }
}

// ---- hidden layer for 4 et-subtiles: weight frags shared across all 4 -----
__device__ inline void hidden_layer4(const unsigned short* __restrict__ Wl,
                                     const float* __restrict__ bp,
                                     const frag (&in)[4][4], frag (&out)[4][4],
                                     int cl, int kg)
{
    #pragma unroll
    for (int nt = 0; nt < 8; ++nt) {
        bf16x8 wf[4];
        #pragma unroll
        for (int ks = 0; ks < 4; ++ks)
            wf[ks] = *reinterpret_cast<const bf16x8*>(
                Wl + swz(nt * 16 + cl, ks * 32 + kg * 8));
        f32x4 bias = *reinterpret_cast<const f32x4*>(bp + nt * 16 + kg * 4);
        #pragma unroll
        for (int et = 0; et < 4; ++et) {
            f32x4 acc = bias;
            #pragma unroll
            for (int ks = 0; ks < 4; ++ks)
                acc = __builtin_amdgcn_mfma_f32_16x16x32_bf16(wf[ks], in[et][ks].v, acc, 0, 0, 0);
            out[et][nt & 3].u[((nt >> 2) << 1) + 0] = pk2(fmaxf(acc[0], 0.f), fmaxf(acc[1], 0.f));
            out[et][nt & 3].u[((nt >> 2) << 1) + 1] = pk2(fmaxf(acc[2], 0.f), fmaxf(acc[3], 0.f));
        }
    }
}

// ---------------- main kernel: persistent, 64-edge wave-tiles --------------
__global__ __launch_bounds__(512, 2)
void edge_kernel(const float* __restrict__ x, const float* __restrict__ ipos,
                 const float* __restrict__ opos, const int* __restrict__ esrc,
                 const int* __restrict__ edst,
                 const unsigned short* __restrict__ wcat,
                 const unsigned short* __restrict__ W1T,
                 const float* __restrict__ b1p, const float* __restrict__ b2p,
                 const float* __restrict__ b3p, const float* __restrict__ b4p,
                 float* __restrict__ agg, float* __restrict__ deg)
{
    extern __shared__ char lds[];
    unsigned short* Wlds = (unsigned short*)lds;   // W2 @0, W3 @16384, W4 @32768

    const int tid  = threadIdx.x;
    const int wv   = __builtin_amdgcn_readfirstlane(tid >> 6);
    const int lane = tid & 63;
    const int cl   = lane & 15;
    const int kg   = lane >> 4;

    // ---- prologue: first tile metadata (lane = edge) ----
    int srcv, dstv; unsigned au0, au1, au2;
    {
        const int eA = (blockIdx.x * 8 + wv) * 64 + lane;
        srcv = esrc[eA]; dstv = edst[eA];
        atomicAdd(&deg[dstv], 1.0f);
        float o0 = opos[dstv * 3 + 0], o1 = opos[dstv * 3 + 1], o2 = opos[dstv * 3 + 2];
        float i0 = ipos[srcv * 3 + 0], i1 = ipos[srcv * 3 + 1], i2 = ipos[srcv * 3 + 2];
        au0 = pk2(o0, o1); au1 = pk2(o2, i0); au2 = pk2(i1, i2);
    }

    // stage 128 KB weight image (once per block)
    {
        const float4* s4 = (const float4*)wcat;
        float4* d4 = (float4*)lds;
        for (int i = tid; i < 8192; i += 512) d4[i] = s4[i];
    }
    __syncthreads();   // the only barrier

    uint2* xs = (uint2*)(lds + 131072 + wv * 4096);   // wave-private [i:8][e:64]

    for (int bt = blockIdx.x; bt < BITER; bt += NBLK) {
        // ---- x gather half 0 (i 0-7) + W1 frag reload: issue first ----
        float4 xg0[4][2];
        {
            const float* xp = x + (size_t)srcv * CI;
            #pragma unroll
            for (int b = 0; b < 4; ++b) {
                const float* xb = xp + (size_t)b * (NIN_ * CI);
                xg0[b][0] = *reinterpret_cast<const float4*>(xb);
                xg0[b][1] = *reinterpret_cast<const float4*>(xb + 4);
            }
        }
        bf16x8 a1w[8];
        #pragma unroll
        for (int nt = 0; nt < 8; ++nt)
            a1w[nt] = *reinterpret_cast<const bf16x8*>(
                W1T + (nt * 16 + cl) * 32 + kg * 8);

        // ---- B1 attr frags from packed regs via shfl ----
        frag b1f[4];
        #pragma unroll
        for (int et = 0; et < 4; ++et) {
            const int sl = et * 16 + cl;
            unsigned s0 = __shfl(au0, sl), s1 = __shfl(au1, sl), s2 = __shfl(au2, sl);
            frag f;
            f.u[0] = (kg == 0) ? s0 : 0u;
            f.u[1] = (kg == 0) ? s1 : 0u;
            f.u[2] = (kg == 0) ? s2 : 0u;
            f.u[3] = 0u;
            b1f[et] = f;
        }

        // ---- layer 1 ----
        frag B2[4][4];
        #pragma unroll
        for (int nt = 0; nt < 8; ++nt) {
            f32x4 bias = *reinterpret_cast<const f32x4*>(b1p + nt * 16 + kg * 4);
            #pragma unroll
            for (int et = 0; et < 4; ++et) {
                f32x4 acc = bias;
                acc = __builtin_amdgcn_mfma_f32_16x16x32_bf16(a1w[nt], b1f[et].v, acc, 0, 0, 0);
                B2[et][nt & 3].u[((nt >> 2) << 1) + 0] = pk2(fmaxf(acc[0], 0.f), fmaxf(acc[1], 0.f));
                B2[et][nt & 3].u[((nt >> 2) << 1) + 1] = pk2(fmaxf(acc[2], 0.f), fmaxf(acc[3], 0.f));
            }
        }

        // ---- prefetch next tile metadata (hidden under layers 2-4) ----
        int nsrc = srcv, ndst = dstv;
        unsigned na0 = au0, na1 = au1, na2 = au2;
        {
            const int nbt = bt + NBLK;
            if (nbt < BITER) {
                const int neA = (nbt * 8 + wv) * 64 + lane;
                nsrc = esrc[neA]; ndst = edst[neA];
                atomicAdd(&deg[ndst], 1.0f);
                float o0 = opos[ndst * 3 + 0], o1 = opos[ndst * 3 + 1], o2 = opos[ndst * 3 + 2];
                float i0 = ipos[nsrc * 3 + 0], i1 = ipos[nsrc * 3 + 1], i2 = ipos[nsrc * 3 + 2];
                na0 = pk2(o0, o1); na1 = pk2(o2, i0); na2 = pk2(i1, i2);
            }
        }

        // ---- layers 2, 3 ----
        frag B3[4][4];
        hidden_layer4(Wlds, b2p, B2, B3, cl, kg);

        // x gather half 1 (i 8-15): issue before L3, consumed after L4-half0
        float4 xg1[4][2];
        {
            const float* xp = x + (size_t)srcv * CI + 8;
            #pragma unroll
            for (int b = 0; b < 4; ++b) {
                const float* xb = xp + (size_t)b * (NIN_ * CI);
                xg1[b][0] = *reinterpret_cast<const float4*>(xb);
                xg1[b][1] = *reinterpret_cast<const float4*>(xb + 4);
            }
        }

        frag B4[4][4];
        hidden_layer4(Wlds + 16384, b3p, B3, B4, cl, kg);

        // ---- layer 4 + fused message, two i-halves through one xs buffer ----
        float macc[4][16];   // [et][b*4 + j]
        #pragma unroll
        for (int et = 0; et < 4; ++et)
            #pragma unroll
            for (int q = 0; q < 16; ++q) macc[et][q] = 0.f;

        const unsigned short* W4l = Wlds + 32768;

        // half 0: xs <- xg0 (i 0-7), nt 0-7
        #pragma unroll
        for (int i2 = 0; i2 < 2; ++i2)
            #pragma unroll
            for (int r = 0; r < 4; ++r) {
                uint2 v;
                v.x = pk2(xg0[0][i2][r], xg0[1][i2][r]);
                v.y = pk2(xg0[2][i2][r], xg0[3][i2][r]);
                xs[(i2 * 4 + r) * 64 + lane] = v;
            }
        #pragma unroll
        for (int nt = 0; nt < 8; ++nt) {
            bf16x8 wf[4];
            #pragma unroll
            for (int ks = 0; ks < 4; ++ks)
                wf[ks] = *reinterpret_cast<const bf16x8*>(
                    W4l + swz(nt * 16 + cl, ks * 32 + kg * 8));
            const float bv = b4p[nt * 16 + cl];
            #pragma unroll
            for (int et = 0; et < 4; ++et) {
                const uint4 xa = *reinterpret_cast<const uint4*>(
                    &xs[nt * 64 + et * 16 + kg * 4]);
                f32x4 acc = {bv, bv, bv, bv};
                #pragma unroll
                for (int ks = 0; ks < 4; ++ks)
                    acc = __builtin_amdgcn_mfma_f32_16x16x32_bf16(B4[et][ks].v, wf[ks], acc, 0, 0, 0);
                const unsigned w01[4] = {xa.x, xa.z, 0, 0};
                const uint4 xb = *reinterpret_cast<const uint4*>(
                    &xs[nt * 64 + et * 16 + kg * 4 + 2]);
                const unsigned w01b[4] = {xa.x, xa.z, xb.x, xb.z};
                const unsigned w23b[4] = {xa.y, xa.w, xb.y, xb.w};
                (void)w01;
                #pragma unroll
                for (int j = 0; j < 4; ++j) {
                    const float x0 = __uint_as_float(w01b[j] << 16);
                    const float x1 = __uint_as_float(w01b[j] & 0xffff0000u);
                    const float x2 = __uint_as_float(w23b[j] << 16);
                    const float x3 = __uint_as_float(w23b[j] & 0xffff0000u);
                    macc[et][0 * 4 + j] = fmaf(x0, acc[j], macc[et][0 * 4 + j]);
                    macc[et][1 * 4 + j] = fmaf(x1, acc[j], macc[et][1 * 4 + j]);
                    macc[et][2 * 4 + j] = fmaf(x2, acc[j], macc[et][2 * 4 + j]);
                    macc[et][3 * 4 + j] = fmaf(x3, acc[j], macc[et][3 * 4 + j]);
                }
            }
        }

        // half 1: xs <- xg1 (i 8-15), nt 8-15
        #pragma unroll
        for (int i2 = 0; i2 < 2; ++i2)
            #pragma unroll
            for (int r = 0; r < 4; ++r) {
                uint2 v;
                v.x = pk2(xg1[0][i2][r], xg1[1][i2][r]);
                v.y = pk2(xg1[2][i2][r], xg1[3][i2][r]);
                xs[(i2 * 4 + r) * 64 + lane] = v;
            }
        #pragma unroll
        for (int nt8 = 0; nt8 < 8; ++nt8) {
            const int nt = 8 + nt8;
            bf16x8 wf[4];
            #pragma unroll
            for (int ks = 0; ks < 4; ++ks)
                wf[ks] = *reinterpret_cast<const bf16x8*>(
                    W4l + swz(nt * 16 + cl, ks * 32 + kg * 8));
            const float bv = b4p[nt * 16 + cl];
            #pragma unroll
            for (int et = 0; et < 4; ++et) {
                const uint4 xa = *reinterpret_cast<const uint4*>(
                    &xs[nt8 * 64 + et * 16 + kg * 4]);
                const uint4 xb = *reinterpret_cast<const uint4*>(
                    &xs[nt8 * 64 + et * 16 + kg * 4 + 2]);
                f32x4 acc = {bv, bv, bv, bv};
                #pragma unroll
                for (int ks = 0; ks < 4; ++ks)
                    acc = __builtin_amdgcn_mfma_f32_16x16x32_bf16(B4[et][ks].v, wf[ks], acc, 0, 0, 0);
                const unsigned w01b[4] = {xa.x, xa.z, xb.x, xb.z};
                const unsigned w23b[4] = {xa.y, xa.w, xb.y, xb.w};
                #pragma unroll
                for (int j = 0; j < 4; ++j) {
                    const float x0 = __uint_as_float(w01b[j] << 16);
                    const float x1 = __uint_as_float(w01b[j] & 0xffff0000u);
                    const float x2 = __uint_as_float(w23b[j] << 16);
                    const float x3 = __uint_as_float(w23b[j] & 0xffff0000u);
                    macc[et][0 * 4 + j] = fmaf(x0, acc[j], macc[et][0 * 4 + j]);
                    macc[et][1 * 4 + j] = fmaf(x1, acc[j], macc[et][1 * 4 + j]);
                    macc[et][2 * 4 + j] = fmaf(x2, acc[j], macc[et][2 * 4 + j]);
                    macc[et][3 * 4 + j] = fmaf(x3, acc[j], macc[et][3 * 4 + j]);
                }
            }
        }

        // ---- scatter: agg layout [b][n][o]; 16 cl lanes = 64 B contiguous ----
        #pragma unroll
        for (int et = 0; et < 4; ++et)
            #pragma unroll
            for (int j = 0; j < 4; ++j) {
                const int d = __shfl(dstv, et * 16 + kg * 4 + j);
                #pragma unroll
                for (int b = 0; b < 4; ++b)
                    atomicAdd(agg + (size_t)b * (NOUT_ * CO) + (size_t)d * CO + cl,
                              macc[et][b * 4 + j]);
            }

        // ---- rotate prefetched metadata ----
        srcv = nsrc; dstv = ndst; au0 = na0; au1 = na1; au2 = na2;
    }
}

// agg layout [b][n][o] == out layout: fully linear finalize, float4
__global__ __launch_bounds__(256)
void finalize_kernel(const float* __restrict__ agg, const float* __restrict__ deg,
                     const float* __restrict__ bias, float* __restrict__ out)
{
    const int idx4 = blockIdx.x * 256 + threadIdx.x;   // over 800000 float4s
    const int n = (idx4 >> 2) % NOUT_;
    const float4 a = reinterpret_cast<const float4*>(agg)[idx4];
    const float dinv = 1.0f / fmaxf(deg[n], 1.0f);
    const float4 bv = reinterpret_cast<const float4*>(bias)[idx4 & 3];
    float4 o;
    o.x = a.x * dinv + bv.x;
    o.y = a.y * dinv + bv.y;
    o.z = a.z * dinv + bv.z;
    o.w = a.w * dinv + bv.w;
    reinterpret_cast<float4*>(out)[idx4] = o;
}

extern "C" void kernel_launch(void* const* d_in, const int* in_sizes, int n_in,
                              void* d_out, int out_size, void* d_ws, size_t ws_size,
                              hipStream_t stream)
{
    const float* x    = (const float*)d_in[0];
    const float* ipos = (const float*)d_in[1];
    const float* opos = (const float*)d_in[2];
    const int*   esrc = (const int*)d_in[3];
    const int*   edst = (const int*)d_in[4];
    const float* w1   = (const float*)d_in[5];
    const float* b1   = (const float*)d_in[6];
    const float* w2   = (const float*)d_in[7];
    const float* b2   = (const float*)d_in[8];
    const float* w3   = (const float*)d_in[9];
    const float* b3   = (const float*)d_in[10];
    const float* w4   = (const float*)d_in[11];
    const float* b4   = (const float*)d_in[12];
    const float* bias = (const float*)d_in[14];

    // Weight scratch in d_out's head (~139 KB); finalize overwrites it.
    char* ob = (char*)d_out;
    unsigned short* wcat = (unsigned short*)ob;              // 131072 B LDS image
    unsigned short* W1T  = (unsigned short*)(ob + 131072);   // 8192 B
    float* b1p = (float*)(ob + 139264);
    float* b2p = (float*)(ob + 139776);
    float* b3p = (float*)(ob + 140288);
    float* b4p = (float*)(ob + 140800);                      // ends 141824 B

    float* agg = (float*)d_ws;                               // [b][n][o]
    float* deg = agg + (size_t)B_ * NOUT_ * CO;

    hipMemsetAsync(d_ws, 0,
                   ((size_t)B_ * NOUT_ * CO + NOUT_) * sizeof(float), stream);

    prep_kernel<<<275, 256, 0, stream>>>(w1, w2, w3, w4, b1, b2, b3, b4,
                                         wcat, W1T, b1p, b2p, b3p, b4p);

    hipFuncSetAttribute(reinterpret_cast<const void*>(edge_kernel),
                        hipFuncAttributeMaxDynamicSharedMemorySize,
                        (int)LDS_BYTES);
    edge_kernel<<<NBLK, 512, LDS_BYTES, stream>>>(
        x, ipos, opos, esrc, edst, wcat, W1T, b1p, b2p, b3p, b4p, agg, deg);

    finalize_kernel<<<B_ * NOUT_ * CO / 4 / 256, 256, 0, stream>>>(
        agg, deg, bias, (float*)d_out);
}

// Round 9
// 362.997 us; speedup vs baseline: 1.0949x; 1.0949x over previous
//
#include <hip/hip_runtime.h>
#include <hip/hip_bf16.h>
#include <cstdint>

constexpr int B_    = 4;
constexpr int NIN_  = 50000;
constexpr int NOUT_ = 50000;
constexpr int E_    = 819200;
constexpr int CI    = 16;
constexpr int CO    = 16;
constexpr int Hh    = 100;

constexpr int NBLK   = 256;           // persistent blocks (1 per CU)
constexpr int BITER  = E_ / 512;      // 1600 block-iterations (8 waves x 64 edges)
constexpr size_t LDS_BYTES = 163840;  // 128 KB weights + 8 waves x 4 KB xs

typedef __attribute__((ext_vector_type(8))) short bf16x8;
typedef __attribute__((ext_vector_type(4))) float f32x4;

union frag { bf16x8 v; unsigned u[4]; };

__device__ inline unsigned pk2(float a, float b) {
    unsigned r;
    asm("v_cvt_pk_bf16_f32 %0, %1, %2" : "=v"(r) : "v"(a), "v"(b));
    return r;
}

// 16B-chunk XOR bank swizzle within a 128-bf16 row (verified rounds 2-8)
__device__ inline int chunkXor(int r) { return ((r & 7) << 3) ^ ((r & 8) << 1); }
__device__ inline int swz(int r, int k) { return r * 128 + (k ^ chunkXor(r)); }

// sigma-wiring: out-wire at D(nt,kg,q) is consumed at k_eff = sigma(m) =
// (nt&3)*32 + kg*8 + (nt>>2)*4 + q ; prep bakes sigma^-1 into the weight image.

// ---------------- prep: swizzled+sigma'd bf16 weight image ------------------
__global__ __launch_bounds__(256)
void prep_kernel(const float* __restrict__ w1, const float* __restrict__ w2,
                 const float* __restrict__ w3, const float* __restrict__ w4,
                 const float* __restrict__ b1, const float* __restrict__ b2,
                 const float* __restrict__ b3, const float* __restrict__ b4,
                 unsigned short* __restrict__ wcat, unsigned short* __restrict__ W1T,
                 float* __restrict__ b1p, float* __restrict__ b2p,
                 float* __restrict__ b3p, float* __restrict__ b4p)
{
    const int i = blockIdx.x * 256 + threadIdx.x;
    auto bf = [](float f) {
        __hip_bfloat16 h = __float2bfloat16(f);
        return *reinterpret_cast<unsigned short*>(&h);
    };
    auto inv = [](int kpos) {   // sigma^-1
        return ((kpos >> 2) & 1) * 64 + ((kpos >> 5) & 3) * 16 +
               ((kpos >> 3) & 3) * 4 + (kpos & 3);
    };
    if (i < 32768) {                     // W2 [0,16384), W3 [16384,32768)
        int j = i & 16383; int r = j >> 7, kz = j & 127;
        int kpos = kz ^ chunkXor(r);
        int u = inv(kpos);
        const float* w = (i < 16384) ? w2 : w3;
        wcat[i] = (r < Hh && u < Hh) ? bf(w[u * Hh + r]) : (unsigned short)0;
    } else if (i < 65536) {              // W4: rows 256 x k 128
        int j = i - 32768; int r = j >> 7, kz = j & 127;
        int kpos = kz ^ chunkXor(r);
        int u = inv(kpos);
        wcat[i] = (u < Hh) ? bf(w4[u * 256 + r]) : (unsigned short)0;
    } else if (i < 69632) {              // W1T [wire:128][k:32]
        int j = i - 65536; int wi = j >> 5, k = j & 31;
        W1T[j] = (k < 6 && wi < Hh) ? bf(w1[k * Hh + wi]) : (unsigned short)0;
    } else if (i < 69760) { int j = i - 69632; b1p[j] = (j < Hh) ? b1[j] : 0.f; }
    else if (i < 69888) { int j = i - 69760; b2p[j] = (j < Hh) ? b2[j] : 0.f; }
    else if (i < 70016) { int j = i - 69888; b3p[j] = (j < Hh) ? b3[j] : 0.f; }
    else if (i < 70272) { int j = i - 70016; b4p[j] = b4[j]; }
}

// ---------------- packx: x[b][s][i] fp32 -> xbf[s][i-pair][b] bf16 ----------
// uint4 per (s, p): { pk2(x0[2p],x1[2p]), pk2(x2[2p],x3[2p]),
//                     pk2(x0[2p+1],x1[2p+1]), pk2(x2[2p+1],x3[2p+1]) }
__global__ __launch_bounds__(256)
void packx_kernel(const float* __restrict__ x, uint4* __restrict__ xbf4)
{
    const int s = blockIdx.x * 256 + threadIdx.x;
    if (s >= NIN_) return;
    float4 r[4][4];   // [b][quad]
    #pragma unroll
    for (int b = 0; b < 4; ++b) {
        const float* xp = x + ((size_t)b * NIN_ + s) * CI;
        #pragma unroll
        for (int q = 0; q < 4; ++q)
            r[b][q] = *reinterpret_cast<const float4*>(xp + q * 4);
    }
    #pragma unroll
    for (int p = 0; p < 8; ++p) {
        const int q = p >> 1;            // float4 quad
        const int h = (p & 1) * 2;       // element pair within quad
        uint4 v;
        v.x = pk2(((const float*)&r[0][q])[h],     ((const float*)&r[1][q])[h]);
        v.y = pk2(((const float*)&r[2][q])[h],     ((const float*)&r[3][q])[h]);
        v.z = pk2(((const float*)&r[0][q])[h + 1], ((const float*)&r[1][q])[h + 1]);
        v.w = pk2(((const float*)&r[2][q])[h + 1], ((const float*)&r[3][q])[h + 1]);
        xbf4[(size_t)s * 8 + p] = v;
    }
}

// ---- hidden layer for 4 et-subtiles: weight frags shared across all 4 -----
__device__ inline void hidden_layer4(const unsigned short* __restrict__ Wl,
                                     const float* __restrict__ bp,
                                     const frag (&in)[4][4], frag (&out)[4][4],
                                     int cl, int kg)
{
    #pragma unroll
    for (int nt = 0; nt < 8; ++nt) {
        bf16x8 wf[4];
        #pragma unroll
        for (int ks = 0; ks < 4; ++ks)
            wf[ks] = *reinterpret_cast<const bf16x8*>(
                Wl + swz(nt * 16 + cl, ks * 32 + kg * 8));
        f32x4 bias = *reinterpret_cast<const f32x4*>(bp + nt * 16 + kg * 4);
        #pragma unroll
        for (int et = 0; et < 4; ++et) {
            f32x4 acc = bias;
            #pragma unroll
            for (int ks = 0; ks < 4; ++ks)
                acc = __builtin_amdgcn_mfma_f32_16x16x32_bf16(wf[ks], in[et][ks].v, acc, 0, 0, 0);
            out[et][nt & 3].u[((nt >> 2) << 1) + 0] = pk2(fmaxf(acc[0], 0.f), fmaxf(acc[1], 0.f));
            out[et][nt & 3].u[((nt >> 2) << 1) + 1] = pk2(fmaxf(acc[2], 0.f), fmaxf(acc[3], 0.f));
        }
    }
}

// ---------------- main kernel: persistent, 64-edge wave-tiles --------------
__global__ __launch_bounds__(512)
__attribute__((amdgpu_waves_per_eu(2, 2)))
void edge_kernel(const uint4* __restrict__ xbf4, const float* __restrict__ ipos,
                 const float* __restrict__ opos, const int* __restrict__ esrc,
                 const int* __restrict__ edst,
                 const unsigned short* __restrict__ wcat,
                 const unsigned short* __restrict__ W1T,
                 const float* __restrict__ b1p, const float* __restrict__ b2p,
                 const float* __restrict__ b3p, const float* __restrict__ b4p,
                 float* __restrict__ agg, float* __restrict__ deg)
{
    extern __shared__ char lds[];
    unsigned short* Wlds = (unsigned short*)lds;   // W2 @0, W3 @16384, W4 @32768

    const int tid  = threadIdx.x;
    const int wv   = __builtin_amdgcn_readfirstlane(tid >> 6);
    const int lane = tid & 63;
    const int cl   = lane & 15;
    const int kg   = lane >> 4;

    // ---- prologue: first tile metadata (lane = edge) ----
    int srcv, dstv; unsigned au0, au1, au2;
    {
        const int eA = (blockIdx.x * 8 + wv) * 64 + lane;
        srcv = esrc[eA]; dstv = edst[eA];
        atomicAdd(&deg[dstv], 1.0f);
        float o0 = opos[dstv * 3 + 0], o1 = opos[dstv * 3 + 1], o2 = opos[dstv * 3 + 2];
        float i0 = ipos[srcv * 3 + 0], i1 = ipos[srcv * 3 + 1], i2 = ipos[srcv * 3 + 2];
        au0 = pk2(o0, o1); au1 = pk2(o2, i0); au2 = pk2(i1, i2);
    }

    // stage 128 KB weight image (once per block)
    {
        const float4* s4 = (const float4*)wcat;
        float4* d4 = (float4*)lds;
        for (int i = tid; i < 8192; i += 512) d4[i] = s4[i];
    }
    __syncthreads();   // the only barrier

    uint2* xs = (uint2*)(lds + 131072 + wv * 4096);   // wave-private [i:8][e:64]

    for (int bt = blockIdx.x; bt < BITER; bt += NBLK) {
        // ---- x load: 8 x uint4 = full bf16-packed row (issue first) ----
        uint4 xq[8];
        {
            const uint4* xp = xbf4 + (size_t)srcv * 8;
            #pragma unroll
            for (int p = 0; p < 8; ++p) xq[p] = xp[p];
        }
        bf16x8 a1w[8];
        #pragma unroll
        for (int nt = 0; nt < 8; ++nt)
            a1w[nt] = *reinterpret_cast<const bf16x8*>(
                W1T + (nt * 16 + cl) * 32 + kg * 8);

        // ---- B1 attr frags from packed regs via shfl ----
        frag b1f[4];
        #pragma unroll
        for (int et = 0; et < 4; ++et) {
            const int sl = et * 16 + cl;
            unsigned s0 = __shfl(au0, sl), s1 = __shfl(au1, sl), s2 = __shfl(au2, sl);
            frag f;
            f.u[0] = (kg == 0) ? s0 : 0u;
            f.u[1] = (kg == 0) ? s1 : 0u;
            f.u[2] = (kg == 0) ? s2 : 0u;
            f.u[3] = 0u;
            b1f[et] = f;
        }

        // ---- layer 1 ----
        frag B2[4][4];
        #pragma unroll
        for (int nt = 0; nt < 8; ++nt) {
            f32x4 bias = *reinterpret_cast<const f32x4*>(b1p + nt * 16 + kg * 4);
            #pragma unroll
            for (int et = 0; et < 4; ++et) {
                f32x4 acc = bias;
                acc = __builtin_amdgcn_mfma_f32_16x16x32_bf16(a1w[nt], b1f[et].v, acc, 0, 0, 0);
                B2[et][nt & 3].u[((nt >> 2) << 1) + 0] = pk2(fmaxf(acc[0], 0.f), fmaxf(acc[1], 0.f));
                B2[et][nt & 3].u[((nt >> 2) << 1) + 1] = pk2(fmaxf(acc[2], 0.f), fmaxf(acc[3], 0.f));
            }
        }

        // ---- prefetch next tile metadata (hidden under layers 2-4) ----
        int nsrc = srcv, ndst = dstv;
        unsigned na0 = au0, na1 = au1, na2 = au2;
        {
            const int nbt = bt + NBLK;
            if (nbt < BITER) {
                const int neA = (nbt * 8 + wv) * 64 + lane;
                nsrc = esrc[neA]; ndst = edst[neA];
                atomicAdd(&deg[ndst], 1.0f);
                float o0 = opos[ndst * 3 + 0], o1 = opos[ndst * 3 + 1], o2 = opos[ndst * 3 + 2];
                float i0 = ipos[nsrc * 3 + 0], i1 = ipos[nsrc * 3 + 1], i2 = ipos[nsrc * 3 + 2];
                na0 = pk2(o0, o1); na1 = pk2(o2, i0); na2 = pk2(i1, i2);
            }
        }

        // ---- layers 2, 3 ----
        frag B3[4][4];
        hidden_layer4(Wlds, b2p, B2, B3, cl, kg);
        frag B4[4][4];
        hidden_layer4(Wlds + 16384, b3p, B3, B4, cl, kg);

        // ---- layer 4 + fused message, two i-halves through one xs buffer ----
        float macc[4][16];   // [et][b*4 + j]
        #pragma unroll
        for (int et = 0; et < 4; ++et)
            #pragma unroll
            for (int q = 0; q < 16; ++q) macc[et][q] = 0.f;

        const unsigned short* W4l = Wlds + 32768;

        // half 0: xs <- xq[0..3] (i 0-7), nt 0-7
        #pragma unroll
        for (int p = 0; p < 4; ++p) {
            xs[(2 * p + 0) * 64 + lane] = make_uint2(xq[p].x, xq[p].y);
            xs[(2 * p + 1) * 64 + lane] = make_uint2(xq[p].z, xq[p].w);
        }
        #pragma unroll
        for (int nt = 0; nt < 8; ++nt) {
            bf16x8 wf[4];
            #pragma unroll
            for (int ks = 0; ks < 4; ++ks)
                wf[ks] = *reinterpret_cast<const bf16x8*>(
                    W4l + swz(nt * 16 + cl, ks * 32 + kg * 8));
            const float bv = b4p[nt * 16 + cl];
            #pragma unroll
            for (int et = 0; et < 4; ++et) {
                const uint4 xa = *reinterpret_cast<const uint4*>(
                    &xs[nt * 64 + et * 16 + kg * 4]);
                const uint4 xb = *reinterpret_cast<const uint4*>(
                    &xs[nt * 64 + et * 16 + kg * 4 + 2]);
                f32x4 acc = {bv, bv, bv, bv};
                #pragma unroll
                for (int ks = 0; ks < 4; ++ks)
                    acc = __builtin_amdgcn_mfma_f32_16x16x32_bf16(B4[et][ks].v, wf[ks], acc, 0, 0, 0);
                const unsigned w01b[4] = {xa.x, xa.z, xb.x, xb.z};
                const unsigned w23b[4] = {xa.y, xa.w, xb.y, xb.w};
                #pragma unroll
                for (int j = 0; j < 4; ++j) {
                    const float x0 = __uint_as_float(w01b[j] << 16);
                    const float x1 = __uint_as_float(w01b[j] & 0xffff0000u);
                    const float x2 = __uint_as_float(w23b[j] << 16);
                    const float x3 = __uint_as_float(w23b[j] & 0xffff0000u);
                    macc[et][0 * 4 + j] = fmaf(x0, acc[j], macc[et][0 * 4 + j]);
                    macc[et][1 * 4 + j] = fmaf(x1, acc[j], macc[et][1 * 4 + j]);
                    macc[et][2 * 4 + j] = fmaf(x2, acc[j], macc[et][2 * 4 + j]);
                    macc[et][3 * 4 + j] = fmaf(x3, acc[j], macc[et][3 * 4 + j]);
                }
            }
        }

        // half 1: xs <- xq[4..7] (i 8-15), nt 8-15
        #pragma unroll
        for (int p = 0; p < 4; ++p) {
            xs[(2 * p + 0) * 64 + lane] = make_uint2(xq[4 + p].x, xq[4 + p].y);
            xs[(2 * p + 1) * 64 + lane] = make_uint2(xq[4 + p].z, xq[4 + p].w);
        }
        #pragma unroll
        for (int nt8 = 0; nt8 < 8; ++nt8) {
            const int nt = 8 + nt8;
            bf16x8 wf[4];
            #pragma unroll
            for (int ks = 0; ks < 4; ++ks)
                wf[ks] = *reinterpret_cast<const bf16x8*>(
                    W4l + swz(nt * 16 + cl, ks * 32 + kg * 8));
            const float bv = b4p[nt * 16 + cl];
            #pragma unroll
            for (int et = 0; et < 4; ++et) {
                const uint4 xa = *reinterpret_cast<const uint4*>(
                    &xs[nt8 * 64 + et * 16 + kg * 4]);
                const uint4 xb = *reinterpret_cast<const uint4*>(
                    &xs[nt8 * 64 + et * 16 + kg * 4 + 2]);
                f32x4 acc = {bv, bv, bv, bv};
                #pragma unroll
                for (int ks = 0; ks < 4; ++ks)
                    acc = __builtin_amdgcn_mfma_f32_16x16x32_bf16(B4[et][ks].v, wf[ks], acc, 0, 0, 0);
                const unsigned w01b[4] = {xa.x, xa.z, xb.x, xb.z};
                const unsigned w23b[4] = {xa.y, xa.w, xb.y, xb.w};
                #pragma unroll
                for (int j = 0; j < 4; ++j) {
                    const float x0 = __uint_as_float(w01b[j] << 16);
                    const float x1 = __uint_as_float(w01b[j] & 0xffff0000u);
                    const float x2 = __uint_as_float(w23b[j] << 16);
                    const float x3 = __uint_as_float(w23b[j] & 0xffff0000u);
                    macc[et][0 * 4 + j] = fmaf(x0, acc[j], macc[et][0 * 4 + j]);
                    macc[et][1 * 4 + j] = fmaf(x1, acc[j], macc[et][1 * 4 + j]);
                    macc[et][2 * 4 + j] = fmaf(x2, acc[j], macc[et][2 * 4 + j]);
                    macc[et][3 * 4 + j] = fmaf(x3, acc[j], macc[et][3 * 4 + j]);
                }
            }
        }

        // ---- scatter: agg layout [b][n][o]; 16 cl lanes = 64 B contiguous ----
        #pragma unroll
        for (int et = 0; et < 4; ++et)
            #pragma unroll
            for (int j = 0; j < 4; ++j) {
                const int d = __shfl(dstv, et * 16 + kg * 4 + j);
                #pragma unroll
                for (int b = 0; b < 4; ++b)
                    atomicAdd(agg + (size_t)b * (NOUT_ * CO) + (size_t)d * CO + cl,
                              macc[et][b * 4 + j]);
            }

        // ---- rotate prefetched metadata ----
        srcv = nsrc; dstv = ndst; au0 = na0; au1 = na1; au2 = na2;
    }
}

// agg layout [b][n][o] == out layout: fully linear finalize, float4
__global__ __launch_bounds__(256)
void finalize_kernel(const float* __restrict__ agg, const float* __restrict__ deg,
                     const float* __restrict__ bias, float* __restrict__ out)
{
    const int idx4 = blockIdx.x * 256 + threadIdx.x;   // over 800000 float4s
    const int n = (idx4 >> 2) % NOUT_;
    const float4 a = reinterpret_cast<const float4*>(agg)[idx4];
    const float dinv = 1.0f / fmaxf(deg[n], 1.0f);
    const float4 bv = reinterpret_cast<const float4*>(bias)[idx4 & 3];
    float4 o;
    o.x = a.x * dinv + bv.x;
    o.y = a.y * dinv + bv.y;
    o.z = a.z * dinv + bv.z;
    o.w = a.w * dinv + bv.w;
    reinterpret_cast<float4*>(out)[idx4] = o;
}

extern "C" void kernel_launch(void* const* d_in, const int* in_sizes, int n_in,
                              void* d_out, int out_size, void* d_ws, size_t ws_size,
                              hipStream_t stream)
{
    const float* x    = (const float*)d_in[0];
    const float* ipos = (const float*)d_in[1];
    const float* opos = (const float*)d_in[2];
    const int*   esrc = (const int*)d_in[3];
    const int*   edst = (const int*)d_in[4];
    const float* w1   = (const float*)d_in[5];
    const float* b1   = (const float*)d_in[6];
    const float* w2   = (const float*)d_in[7];
    const float* b2   = (const float*)d_in[8];
    const float* w3   = (const float*)d_in[9];
    const float* b3   = (const float*)d_in[10];
    const float* w4   = (const float*)d_in[11];
    const float* b4   = (const float*)d_in[12];
    const float* bias = (const float*)d_in[14];

    // Scratch in d_out's head (finalize overwrites it at the end):
    //   wcat 128KB | W1T 8KB | biases | xbf 6.4MB  -> total ~6.55MB < 12.8MB
    char* ob = (char*)d_out;
    unsigned short* wcat = (unsigned short*)ob;              // 131072 B
    unsigned short* W1T  = (unsigned short*)(ob + 131072);   // 8192 B
    float* b1p = (float*)(ob + 139264);
    float* b2p = (float*)(ob + 139776);
    float* b3p = (float*)(ob + 140288);
    float* b4p = (float*)(ob + 140800);                      // ends 141824 B
    uint4* xbf4 = (uint4*)(ob + 147456);                     // 6.4 MB

    float* agg = (float*)d_ws;                               // [b][n][o]
    float* deg = agg + (size_t)B_ * NOUT_ * CO;

    hipMemsetAsync(d_ws, 0,
                   ((size_t)B_ * NOUT_ * CO + NOUT_) * sizeof(float), stream);

    prep_kernel<<<275, 256, 0, stream>>>(w1, w2, w3, w4, b1, b2, b3, b4,
                                         wcat, W1T, b1p, b2p, b3p, b4p);
    packx_kernel<<<(NIN_ + 255) / 256, 256, 0, stream>>>(x, xbf4);

    hipFuncSetAttribute(reinterpret_cast<const void*>(edge_kernel),
                        hipFuncAttributeMaxDynamicSharedMemorySize,
                        (int)LDS_BYTES);
    edge_kernel<<<NBLK, 512, LDS_BYTES, stream>>>(
        xbf4, ipos, opos, esrc, edst, wcat, W1T, b1p, b2p, b3p, b4p, agg, deg);

    finalize_kernel<<<B_ * NOUT_ * CO / 4 / 256, 256, 0, stream>>>(
        agg, deg, bias, (float*)d_out);
}